// Round 1
// baseline (1232.269 us; speedup 1.0000x reference)
//
#include <hip/hip_runtime.h>

#define N_NODES 100000
#define N_EDGES 3200000
#define EPS 1e-5f

// ---- workspace layout (bytes) ----
// [0,       1024)    : stats  (8 doubles: sum[4], sumsq[4])
// [1024,    401024)  : cnt    (int[100000])
// [401024,  1201024) : agg1   (float[100000*2]) encoder aggregation
// [1201024, 1601024) : invcnt (float[100000])
// [1601024, 3201024) : xn     (float[100000*4]) normalized features
// zero region each launch: [0, 1201024)

__global__ __launch_bounds__(256) void k_bn_stats(const float* __restrict__ x,
                                                  double* __restrict__ stats) {
    int i = blockIdx.x * 256 + threadIdx.x;
    float4 v = make_float4(0.f, 0.f, 0.f, 0.f);
    if (i < N_NODES) v = ((const float4*)x)[i];
    double a[8];
    a[0] = v.x; a[1] = v.y; a[2] = v.z; a[3] = v.w;
    a[4] = (double)v.x * v.x; a[5] = (double)v.y * v.y;
    a[6] = (double)v.z * v.z; a[7] = (double)v.w * v.w;
    // wave(64) butterfly reduce
    #pragma unroll
    for (int off = 32; off > 0; off >>= 1) {
        #pragma unroll
        for (int j = 0; j < 8; j++) a[j] += __shfl_down(a[j], off);
    }
    __shared__ double smem[4][8];
    int wave = threadIdx.x >> 6;
    int lane = threadIdx.x & 63;
    if (lane == 0) {
        #pragma unroll
        for (int j = 0; j < 8; j++) smem[wave][j] = a[j];
    }
    __syncthreads();
    if (threadIdx.x == 0) {
        #pragma unroll
        for (int j = 0; j < 8; j++) {
            double t = smem[0][j] + smem[1][j] + smem[2][j] + smem[3][j];
            atomicAdd(&stats[j], t);
        }
    }
}

__global__ __launch_bounds__(256) void k_normalize(const float* __restrict__ x,
                                                   const double* __restrict__ stats,
                                                   const float* __restrict__ bn_w,
                                                   const float* __restrict__ bn_b,
                                                   float* __restrict__ xn) {
    int i = blockIdx.x * 256 + threadIdx.x;
    if (i >= N_NODES) return;
    const double inv_n = 1.0 / (double)N_NODES;
    float mu[4], sc[4], sh[4];
    #pragma unroll
    for (int d = 0; d < 4; d++) {
        double m  = stats[d] * inv_n;
        double vr = stats[4 + d] * inv_n - m * m;
        float rs  = (float)(1.0 / sqrt(vr + (double)EPS));
        mu[d] = (float)m;
        sc[d] = rs * bn_w[d];
        sh[d] = bn_b[d];
    }
    float4 v = ((const float4*)x)[i];
    float4 o;
    o.x = (v.x - mu[0]) * sc[0] + sh[0];
    o.y = (v.y - mu[1]) * sc[1] + sh[1];
    o.z = (v.z - mu[2]) * sc[2] + sh[2];
    o.w = (v.w - mu[3]) * sc[3] + sh[3];
    ((float4*)xn)[i] = o;
}

// Encoder EdgeConv: in 8 -> 32 -> 32 -> 2, relu on all three layers.
// Also accumulates in-degree counts.
__global__ __launch_bounds__(256) void k_enc(const float* __restrict__ xn,
                                             const int* __restrict__ ei,
                                             float* __restrict__ agg1,
                                             int* __restrict__ cnt,
                                             const float* __restrict__ w1,
                                             const float* __restrict__ b1,
                                             const float* __restrict__ w2,
                                             const float* __restrict__ b2,
                                             const float* __restrict__ w3,
                                             const float* __restrict__ b3) {
    int e = blockIdx.x * 256 + threadIdx.x;
    if (e >= N_EDGES) return;
    int s = ei[e];
    int d = ei[N_EDGES + e];
    float4 xi = ((const float4*)xn)[d];
    float4 xj = ((const float4*)xn)[s];
    float in[8];
    in[0] = xi.x; in[1] = xi.y; in[2] = xi.z; in[3] = xi.w;
    in[4] = xj.x - xi.x; in[5] = xj.y - xi.y; in[6] = xj.z - xi.z; in[7] = xj.w - xi.w;

    float h1[32];
    #pragma unroll
    for (int j = 0; j < 32; j++) h1[j] = b1[j];
    #pragma unroll
    for (int k = 0; k < 8; k++) {
        float v = in[k];
        #pragma unroll
        for (int j = 0; j < 32; j++) h1[j] = fmaf(v, w1[k * 32 + j], h1[j]);
    }
    #pragma unroll
    for (int j = 0; j < 32; j++) h1[j] = fmaxf(h1[j], 0.f);

    float h2[32];
    #pragma unroll
    for (int j = 0; j < 32; j++) h2[j] = b2[j];
    #pragma unroll
    for (int k = 0; k < 32; k++) {
        float v = h1[k];
        #pragma unroll
        for (int j = 0; j < 32; j++) h2[j] = fmaf(v, w2[k * 32 + j], h2[j]);
    }
    #pragma unroll
    for (int j = 0; j < 32; j++) h2[j] = fmaxf(h2[j], 0.f);

    float o0 = b3[0], o1 = b3[1];
    #pragma unroll
    for (int k = 0; k < 32; k++) {
        o0 = fmaf(h2[k], w3[2 * k + 0], o0);
        o1 = fmaf(h2[k], w3[2 * k + 1], o1);
    }
    o0 = fmaxf(o0, 0.f);
    o1 = fmaxf(o1, 0.f);
    atomicAdd(&agg1[2 * d + 0], o0);
    atomicAdd(&agg1[2 * d + 1], o1);
    atomicAdd(&cnt[d], 1);
}

// mid: invcnt = 1/max(cnt,1);  agg1 *= invcnt  (mean aggregation)
__global__ __launch_bounds__(256) void k_mid(float* __restrict__ agg1,
                                             const int* __restrict__ cnt,
                                             float* __restrict__ invcnt) {
    int i = blockIdx.x * 256 + threadIdx.x;
    if (i >= N_NODES) return;
    int c = cnt[i];
    float ic = 1.0f / (float)(c > 1 ? c : 1);
    invcnt[i] = ic;
    float2* a2 = (float2*)agg1;
    float2 v = a2[i];
    v.x *= ic; v.y *= ic;
    a2[i] = v;
}

// Decoder EdgeConv: in 4 -> 32 -> 32 -> 4, relu on first two layers only.
__global__ __launch_bounds__(256) void k_dec(const float* __restrict__ henc,
                                             const int* __restrict__ ei,
                                             float* __restrict__ out,
                                             const float* __restrict__ w1,
                                             const float* __restrict__ b1,
                                             const float* __restrict__ w2,
                                             const float* __restrict__ b2,
                                             const float* __restrict__ w3,
                                             const float* __restrict__ b3) {
    int e = blockIdx.x * 256 + threadIdx.x;
    if (e >= N_EDGES) return;
    int s = ei[e];
    int d = ei[N_EDGES + e];
    float2 hi = ((const float2*)henc)[d];
    float2 hj = ((const float2*)henc)[s];
    float in[4];
    in[0] = hi.x; in[1] = hi.y;
    in[2] = hj.x - hi.x; in[3] = hj.y - hi.y;

    float h1[32];
    #pragma unroll
    for (int j = 0; j < 32; j++) h1[j] = b1[j];
    #pragma unroll
    for (int k = 0; k < 4; k++) {
        float v = in[k];
        #pragma unroll
        for (int j = 0; j < 32; j++) h1[j] = fmaf(v, w1[k * 32 + j], h1[j]);
    }
    #pragma unroll
    for (int j = 0; j < 32; j++) h1[j] = fmaxf(h1[j], 0.f);

    float h2[32];
    #pragma unroll
    for (int j = 0; j < 32; j++) h2[j] = b2[j];
    #pragma unroll
    for (int k = 0; k < 32; k++) {
        float v = h1[k];
        #pragma unroll
        for (int j = 0; j < 32; j++) h2[j] = fmaf(v, w2[k * 32 + j], h2[j]);
    }
    #pragma unroll
    for (int j = 0; j < 32; j++) h2[j] = fmaxf(h2[j], 0.f);

    float o[4];
    #pragma unroll
    for (int j = 0; j < 4; j++) o[j] = b3[j];
    #pragma unroll
    for (int k = 0; k < 32; k++) {
        float v = h2[k];
        #pragma unroll
        for (int j = 0; j < 4; j++) o[j] = fmaf(v, w3[4 * k + j], o[j]);
    }
    // no final relu
    #pragma unroll
    for (int j = 0; j < 4; j++) atomicAdd(&out[4 * d + j], o[j]);
}

__global__ __launch_bounds__(256) void k_fin(float* __restrict__ out,
                                             const float* __restrict__ invcnt) {
    int i = blockIdx.x * 256 + threadIdx.x;
    if (i >= N_NODES) return;
    float ic = invcnt[i];
    float4* o4 = (float4*)out;
    float4 v = o4[i];
    v.x *= ic; v.y *= ic; v.z *= ic; v.w *= ic;
    o4[i] = v;
}

extern "C" void kernel_launch(void* const* d_in, const int* in_sizes, int n_in,
                              void* d_out, int out_size, void* d_ws, size_t ws_size,
                              hipStream_t stream) {
    const float* x    = (const float*)d_in[0];
    const int*   ei   = (const int*)d_in[1];
    const float* bn_w = (const float*)d_in[2];
    const float* bn_b = (const float*)d_in[3];
    const float* ew1  = (const float*)d_in[4];
    const float* eb1  = (const float*)d_in[5];
    const float* ew2  = (const float*)d_in[6];
    const float* eb2  = (const float*)d_in[7];
    const float* ew3  = (const float*)d_in[8];
    const float* eb3  = (const float*)d_in[9];
    const float* dw1  = (const float*)d_in[10];
    const float* db1  = (const float*)d_in[11];
    const float* dw2  = (const float*)d_in[12];
    const float* db2  = (const float*)d_in[13];
    const float* dw3  = (const float*)d_in[14];
    const float* db3  = (const float*)d_in[15];

    char* ws = (char*)d_ws;
    double* stats  = (double*)(ws);
    int*    cnt    = (int*)(ws + 1024);
    float*  agg1   = (float*)(ws + 401024);
    float*  invcnt = (float*)(ws + 1201024);
    float*  xn     = (float*)(ws + 1601024);
    float*  out    = (float*)d_out;

    // zero: stats + cnt + agg1, and the atomic output accumulator
    hipMemsetAsync(ws, 0, 1201024, stream);
    hipMemsetAsync(d_out, 0, (size_t)out_size * sizeof(float), stream);

    const int nodeBlocks = (N_NODES + 255) / 256;   // 391
    const int edgeBlocks = (N_EDGES + 255) / 256;   // 12500

    k_bn_stats<<<nodeBlocks, 256, 0, stream>>>(x, stats);
    k_normalize<<<nodeBlocks, 256, 0, stream>>>(x, stats, bn_w, bn_b, xn);
    k_enc<<<edgeBlocks, 256, 0, stream>>>(xn, ei, agg1, cnt, ew1, eb1, ew2, eb2, ew3, eb3);
    k_mid<<<nodeBlocks, 256, 0, stream>>>(agg1, cnt, invcnt);
    k_dec<<<edgeBlocks, 256, 0, stream>>>(agg1, ei, out, dw1, db1, dw2, db2, dw3, db3);
    k_fin<<<nodeBlocks, 256, 0, stream>>>(out, invcnt);
}

// Round 2
// 932.737 us; speedup vs baseline: 1.3211x; 1.3211x over previous
//
#include <hip/hip_runtime.h>

#define N_NODES 100000
#define N_EDGES 3200000
#define EPS 1e-5f

// ---- workspace layout (bytes) ----
// OFF_STATS  = 0         : 8 doubles (bn sums)                  [zeroed]
// OFF_CNT    = 1024      : int[100000] in-degree histogram      [zeroed]
// OFF_ROWPTR = 401280    : int[100001] CSR row pointers
// OFF_INVCNT = 801536    : float[100000] 1/max(cnt,1)
// OFF_AGG1   = 1201536   : float[100000*2] encoder node output
// OFF_XN     = 2001536   : float[100000*4] normalized features
// OFF_RANK   = 3601536   : int[3200000] per-edge rank within dst
// OFF_EID    = 16401536  : int[3200000] CSR-ordered edge ids
// OFF_H      = 29201536  : per-edge MLP outputs; he (float2) and hd (float4)
//                          share this region (enc consumed before dec writes)
// total ≈ 80.4 MB
#define OFF_STATS  0
#define OFF_CNT    1024
#define OFF_ROWPTR 401280
#define OFF_INVCNT 801536
#define OFF_AGG1   1201536
#define OFF_XN     2001536
#define OFF_RANK   3601536
#define OFF_EID    16401536
#define OFF_H      29201536

__global__ __launch_bounds__(256) void k_bn_stats(const float* __restrict__ x,
                                                  double* __restrict__ stats) {
    int i = blockIdx.x * 256 + threadIdx.x;
    float4 v = make_float4(0.f, 0.f, 0.f, 0.f);
    if (i < N_NODES) v = ((const float4*)x)[i];
    double a[8];
    a[0] = v.x; a[1] = v.y; a[2] = v.z; a[3] = v.w;
    a[4] = (double)v.x * v.x; a[5] = (double)v.y * v.y;
    a[6] = (double)v.z * v.z; a[7] = (double)v.w * v.w;
    #pragma unroll
    for (int off = 32; off > 0; off >>= 1) {
        #pragma unroll
        for (int j = 0; j < 8; j++) a[j] += __shfl_down(a[j], off);
    }
    __shared__ double smem[4][8];
    int wave = threadIdx.x >> 6;
    int lane = threadIdx.x & 63;
    if (lane == 0) {
        #pragma unroll
        for (int j = 0; j < 8; j++) smem[wave][j] = a[j];
    }
    __syncthreads();
    if (threadIdx.x == 0) {
        #pragma unroll
        for (int j = 0; j < 8; j++) {
            double t = smem[0][j] + smem[1][j] + smem[2][j] + smem[3][j];
            atomicAdd(&stats[j], t);
        }
    }
}

__global__ __launch_bounds__(256) void k_normalize(const float* __restrict__ x,
                                                   const double* __restrict__ stats,
                                                   const float* __restrict__ bn_w,
                                                   const float* __restrict__ bn_b,
                                                   float* __restrict__ xn) {
    int i = blockIdx.x * 256 + threadIdx.x;
    if (i >= N_NODES) return;
    const double inv_n = 1.0 / (double)N_NODES;
    float mu[4], sc[4], sh[4];
    #pragma unroll
    for (int d = 0; d < 4; d++) {
        double m  = stats[d] * inv_n;
        double vr = stats[4 + d] * inv_n - m * m;
        float rs  = (float)(1.0 / sqrt(vr + (double)EPS));
        mu[d] = (float)m;
        sc[d] = rs * bn_w[d];
        sh[d] = bn_b[d];
    }
    float4 v = ((const float4*)x)[i];
    float4 o;
    o.x = (v.x - mu[0]) * sc[0] + sh[0];
    o.y = (v.y - mu[1]) * sc[1] + sh[1];
    o.z = (v.z - mu[2]) * sc[2] + sh[2];
    o.w = (v.w - mu[3]) * sc[3] + sh[3];
    ((float4*)xn)[i] = o;
}

// rank[e] = position of edge e among edges sharing its dst; cnt[d] = in-degree
__global__ __launch_bounds__(256) void k_rank(const int* __restrict__ ei,
                                              int* __restrict__ cnt,
                                              int* __restrict__ rank) {
    int e = blockIdx.x * 256 + threadIdx.x;
    if (e >= N_EDGES) return;
    int d = ei[N_EDGES + e];
    rank[e] = atomicAdd(&cnt[d], 1);
}

// single-block exclusive scan of cnt -> rowptr[100001]; also invcnt
__global__ __launch_bounds__(1024) void k_scan(const int* __restrict__ cnt,
                                               int* __restrict__ rowptr,
                                               float* __restrict__ invcnt) {
    __shared__ int part[1024];
    const int T = 1024;
    const int CH = (N_NODES + T - 1) / T;   // 98
    int t = threadIdx.x;
    int base = t * CH;
    int sum = 0;
    for (int i = 0; i < CH; i++) {
        int idx = base + i;
        if (idx < N_NODES) sum += cnt[idx];
    }
    part[t] = sum;
    __syncthreads();
    // Hillis-Steele inclusive scan over 1024 partials
    for (int off = 1; off < T; off <<= 1) {
        int v = (t >= off) ? part[t - off] : 0;
        __syncthreads();
        part[t] += v;
        __syncthreads();
    }
    int run = (t == 0) ? 0 : part[t - 1];
    for (int i = 0; i < CH; i++) {
        int idx = base + i;
        if (idx < N_NODES) {
            rowptr[idx] = run;
            int c = cnt[idx];
            invcnt[idx] = 1.0f / (float)(c > 1 ? c : 1);
            run += c;
        }
    }
    if (t == T - 1) rowptr[N_NODES] = run;
}

// eid[rowptr[dst]+rank[e]] = e  (no atomics)
__global__ __launch_bounds__(256) void k_scatter(const int* __restrict__ ei,
                                                 const int* __restrict__ rowptr,
                                                 const int* __restrict__ rank,
                                                 int* __restrict__ eid) {
    int e = blockIdx.x * 256 + threadIdx.x;
    if (e >= N_EDGES) return;
    int d = ei[N_EDGES + e];
    eid[rowptr[d] + rank[e]] = e;
}

// Encoder EdgeConv per-edge MLP: in 8 -> 32 -> 32 -> 2, relu x3. Writes he[e].
__global__ __launch_bounds__(256) void k_enc_edge(const float* __restrict__ xn,
                                                  const int* __restrict__ ei,
                                                  float2* __restrict__ he,
                                                  const float* __restrict__ w1,
                                                  const float* __restrict__ b1,
                                                  const float* __restrict__ w2,
                                                  const float* __restrict__ b2,
                                                  const float* __restrict__ w3,
                                                  const float* __restrict__ b3) {
    int e = blockIdx.x * 256 + threadIdx.x;
    if (e >= N_EDGES) return;
    int s = ei[e];
    int d = ei[N_EDGES + e];
    float4 xi = ((const float4*)xn)[d];
    float4 xj = ((const float4*)xn)[s];
    float in[8];
    in[0] = xi.x; in[1] = xi.y; in[2] = xi.z; in[3] = xi.w;
    in[4] = xj.x - xi.x; in[5] = xj.y - xi.y; in[6] = xj.z - xi.z; in[7] = xj.w - xi.w;

    float h1[32];
    #pragma unroll
    for (int j = 0; j < 32; j++) h1[j] = b1[j];
    #pragma unroll
    for (int k = 0; k < 8; k++) {
        float v = in[k];
        #pragma unroll
        for (int j = 0; j < 32; j++) h1[j] = fmaf(v, w1[k * 32 + j], h1[j]);
    }
    #pragma unroll
    for (int j = 0; j < 32; j++) h1[j] = fmaxf(h1[j], 0.f);

    float h2[32];
    #pragma unroll
    for (int j = 0; j < 32; j++) h2[j] = b2[j];
    #pragma unroll
    for (int k = 0; k < 32; k++) {
        float v = h1[k];
        #pragma unroll
        for (int j = 0; j < 32; j++) h2[j] = fmaf(v, w2[k * 32 + j], h2[j]);
    }
    #pragma unroll
    for (int j = 0; j < 32; j++) h2[j] = fmaxf(h2[j], 0.f);

    float o0 = b3[0], o1 = b3[1];
    #pragma unroll
    for (int k = 0; k < 32; k++) {
        o0 = fmaf(h2[k], w3[2 * k + 0], o0);
        o1 = fmaf(h2[k], w3[2 * k + 1], o1);
    }
    he[e] = make_float2(fmaxf(o0, 0.f), fmaxf(o1, 0.f));
}

// mean-aggregate encoder outputs per node
__global__ __launch_bounds__(256) void k_reduce_enc(const float2* __restrict__ he,
                                                    const int* __restrict__ rowptr,
                                                    const int* __restrict__ eid,
                                                    const float* __restrict__ invcnt,
                                                    float2* __restrict__ agg1) {
    int i = blockIdx.x * 256 + threadIdx.x;
    if (i >= N_NODES) return;
    int p0 = rowptr[i], p1 = rowptr[i + 1];
    float a0 = 0.f, a1 = 0.f;
    for (int p = p0; p < p1; p++) {
        float2 h = he[eid[p]];
        a0 += h.x; a1 += h.y;
    }
    float ic = invcnt[i];
    agg1[i] = make_float2(a0 * ic, a1 * ic);
}

// Decoder EdgeConv per-edge MLP: in 4 -> 32 -> 32 -> 4, relu on first two. Writes hd[e].
__global__ __launch_bounds__(256) void k_dec_edge(const float2* __restrict__ henc,
                                                  const int* __restrict__ ei,
                                                  float4* __restrict__ hd,
                                                  const float* __restrict__ w1,
                                                  const float* __restrict__ b1,
                                                  const float* __restrict__ w2,
                                                  const float* __restrict__ b2,
                                                  const float* __restrict__ w3,
                                                  const float* __restrict__ b3) {
    int e = blockIdx.x * 256 + threadIdx.x;
    if (e >= N_EDGES) return;
    int s = ei[e];
    int d = ei[N_EDGES + e];
    float2 hi = henc[d];
    float2 hj = henc[s];
    float in[4];
    in[0] = hi.x; in[1] = hi.y;
    in[2] = hj.x - hi.x; in[3] = hj.y - hi.y;

    float h1[32];
    #pragma unroll
    for (int j = 0; j < 32; j++) h1[j] = b1[j];
    #pragma unroll
    for (int k = 0; k < 4; k++) {
        float v = in[k];
        #pragma unroll
        for (int j = 0; j < 32; j++) h1[j] = fmaf(v, w1[k * 32 + j], h1[j]);
    }
    #pragma unroll
    for (int j = 0; j < 32; j++) h1[j] = fmaxf(h1[j], 0.f);

    float h2[32];
    #pragma unroll
    for (int j = 0; j < 32; j++) h2[j] = b2[j];
    #pragma unroll
    for (int k = 0; k < 32; k++) {
        float v = h1[k];
        #pragma unroll
        for (int j = 0; j < 32; j++) h2[j] = fmaf(v, w2[k * 32 + j], h2[j]);
    }
    #pragma unroll
    for (int j = 0; j < 32; j++) h2[j] = fmaxf(h2[j], 0.f);

    float o[4];
    #pragma unroll
    for (int j = 0; j < 4; j++) o[j] = b3[j];
    #pragma unroll
    for (int k = 0; k < 32; k++) {
        float v = h2[k];
        #pragma unroll
        for (int j = 0; j < 4; j++) o[j] = fmaf(v, w3[4 * k + j], o[j]);
    }
    hd[e] = make_float4(o[0], o[1], o[2], o[3]);  // no final relu
}

// mean-aggregate decoder outputs per node -> final output
__global__ __launch_bounds__(256) void k_reduce_dec(const float4* __restrict__ hd,
                                                    const int* __restrict__ rowptr,
                                                    const int* __restrict__ eid,
                                                    const float* __restrict__ invcnt,
                                                    float4* __restrict__ out) {
    int i = blockIdx.x * 256 + threadIdx.x;
    if (i >= N_NODES) return;
    int p0 = rowptr[i], p1 = rowptr[i + 1];
    float a0 = 0.f, a1 = 0.f, a2 = 0.f, a3 = 0.f;
    for (int p = p0; p < p1; p++) {
        float4 h = hd[eid[p]];
        a0 += h.x; a1 += h.y; a2 += h.z; a3 += h.w;
    }
    float ic = invcnt[i];
    out[i] = make_float4(a0 * ic, a1 * ic, a2 * ic, a3 * ic);
}

extern "C" void kernel_launch(void* const* d_in, const int* in_sizes, int n_in,
                              void* d_out, int out_size, void* d_ws, size_t ws_size,
                              hipStream_t stream) {
    const float* x    = (const float*)d_in[0];
    const int*   ei   = (const int*)d_in[1];
    const float* bn_w = (const float*)d_in[2];
    const float* bn_b = (const float*)d_in[3];
    const float* ew1  = (const float*)d_in[4];
    const float* eb1  = (const float*)d_in[5];
    const float* ew2  = (const float*)d_in[6];
    const float* eb2  = (const float*)d_in[7];
    const float* ew3  = (const float*)d_in[8];
    const float* eb3  = (const float*)d_in[9];
    const float* dw1  = (const float*)d_in[10];
    const float* db1  = (const float*)d_in[11];
    const float* dw2  = (const float*)d_in[12];
    const float* db2  = (const float*)d_in[13];
    const float* dw3  = (const float*)d_in[14];
    const float* db3  = (const float*)d_in[15];

    char* ws = (char*)d_ws;
    double* stats  = (double*)(ws + OFF_STATS);
    int*    cnt    = (int*)(ws + OFF_CNT);
    int*    rowptr = (int*)(ws + OFF_ROWPTR);
    float*  invcnt = (float*)(ws + OFF_INVCNT);
    float2* agg1   = (float2*)(ws + OFF_AGG1);
    float*  xn     = (float*)(ws + OFF_XN);
    int*    rank   = (int*)(ws + OFF_RANK);
    int*    eid    = (int*)(ws + OFF_EID);
    float2* he     = (float2*)(ws + OFF_H);
    float4* hd     = (float4*)(ws + OFF_H);   // aliased: enc reduce done before dec writes
    float4* out    = (float4*)d_out;

    // zero: stats (1 KB) + cnt (400 KB), contiguous
    hipMemsetAsync(ws, 0, OFF_CNT + N_NODES * sizeof(int), stream);

    const int nodeBlocks = (N_NODES + 255) / 256;   // 391
    const int edgeBlocks = (N_EDGES + 255) / 256;   // 12500

    k_bn_stats<<<nodeBlocks, 256, 0, stream>>>(x, stats);
    k_normalize<<<nodeBlocks, 256, 0, stream>>>(x, stats, bn_w, bn_b, xn);
    k_rank<<<edgeBlocks, 256, 0, stream>>>(ei, cnt, rank);
    k_scan<<<1, 1024, 0, stream>>>(cnt, rowptr, invcnt);
    k_scatter<<<edgeBlocks, 256, 0, stream>>>(ei, rowptr, rank, eid);
    k_enc_edge<<<edgeBlocks, 256, 0, stream>>>(xn, ei, he, ew1, eb1, ew2, eb2, ew3, eb3);
    k_reduce_enc<<<nodeBlocks, 256, 0, stream>>>(he, rowptr, eid, invcnt, agg1);
    k_dec_edge<<<edgeBlocks, 256, 0, stream>>>(agg1, ei, hd, dw1, db1, dw2, db2, dw3, db3);
    k_reduce_dec<<<nodeBlocks, 256, 0, stream>>>(hd, rowptr, eid, invcnt, out);
}

// Round 3
// 575.637 us; speedup vs baseline: 2.1407x; 1.6204x over previous
//
#include <hip/hip_runtime.h>

#define N_NODES 100000
#define N_EDGES 3200000
#define EPS 1e-5f
#define NODE_BLOCKS 391   // ceil(100000/256)

// ---- workspace layout (bytes) ----
#define OFF_STATS  0          // 8 doubles (bn sums)            [zeroed]
#define OFF_CNT    1024       // int[100000] in-degree          [zeroed]
#define OFF_ROWPTR 401280     // int[100001]
#define OFF_INVCNT 801536     // float[100000]
#define OFF_AGG1   1201536    // float2[100000] encoder node out
#define OFF_XN     2001536    // float4[100000] normalized x
#define OFF_RANK   3601536    // int[3200000] rank within dst
#define OFF_BSUM   16401536   // int[391] block sums
#define OFF_BOFF   16404480   // int[391] block offsets
#define OFF_H      16407552   // CSR-ordered edge outputs; he(float2)/hd(float4) aliased
// total ≈ 67.6 MB

__global__ __launch_bounds__(256) void k_bn_stats(const float* __restrict__ x,
                                                  double* __restrict__ stats) {
    int i = blockIdx.x * 256 + threadIdx.x;
    float4 v = make_float4(0.f, 0.f, 0.f, 0.f);
    if (i < N_NODES) v = ((const float4*)x)[i];
    double a[8];
    a[0] = v.x; a[1] = v.y; a[2] = v.z; a[3] = v.w;
    a[4] = (double)v.x * v.x; a[5] = (double)v.y * v.y;
    a[6] = (double)v.z * v.z; a[7] = (double)v.w * v.w;
    #pragma unroll
    for (int off = 32; off > 0; off >>= 1) {
        #pragma unroll
        for (int j = 0; j < 8; j++) a[j] += __shfl_down(a[j], off);
    }
    __shared__ double smem[4][8];
    int wave = threadIdx.x >> 6;
    int lane = threadIdx.x & 63;
    if (lane == 0) {
        #pragma unroll
        for (int j = 0; j < 8; j++) smem[wave][j] = a[j];
    }
    __syncthreads();
    if (threadIdx.x == 0) {
        #pragma unroll
        for (int j = 0; j < 8; j++) {
            double t = smem[0][j] + smem[1][j] + smem[2][j] + smem[3][j];
            atomicAdd(&stats[j], t);
        }
    }
}

__global__ __launch_bounds__(256) void k_normalize(const float* __restrict__ x,
                                                   const double* __restrict__ stats,
                                                   const float* __restrict__ bn_w,
                                                   const float* __restrict__ bn_b,
                                                   float* __restrict__ xn) {
    int i = blockIdx.x * 256 + threadIdx.x;
    if (i >= N_NODES) return;
    const double inv_n = 1.0 / (double)N_NODES;
    float mu[4], sc[4], sh[4];
    #pragma unroll
    for (int d = 0; d < 4; d++) {
        double m  = stats[d] * inv_n;
        double vr = stats[4 + d] * inv_n - m * m;
        float rs  = (float)(1.0 / sqrt(vr + (double)EPS));
        mu[d] = (float)m;
        sc[d] = rs * bn_w[d];
        sh[d] = bn_b[d];
    }
    float4 v = ((const float4*)x)[i];
    float4 o;
    o.x = (v.x - mu[0]) * sc[0] + sh[0];
    o.y = (v.y - mu[1]) * sc[1] + sh[1];
    o.z = (v.z - mu[2]) * sc[2] + sh[2];
    o.w = (v.w - mu[3]) * sc[3] + sh[3];
    ((float4*)xn)[i] = o;
}

// rank[e] = position of edge e among edges sharing its dst; cnt[d] = in-degree
__global__ __launch_bounds__(256) void k_rank(const int* __restrict__ ei,
                                              int* __restrict__ cnt,
                                              int* __restrict__ rank) {
    int e = blockIdx.x * 256 + threadIdx.x;
    if (e >= N_EDGES) return;
    int d = ei[N_EDGES + e];
    rank[e] = atomicAdd(&cnt[d], 1);
}

// scan phase A: per-block sums of cnt; also invcnt
__global__ __launch_bounds__(256) void k_scan_part(const int* __restrict__ cnt,
                                                   int* __restrict__ bsum,
                                                   float* __restrict__ invcnt) {
    int i = blockIdx.x * 256 + threadIdx.x;
    int c = (i < N_NODES) ? cnt[i] : 0;
    if (i < N_NODES) invcnt[i] = 1.0f / (float)(c > 1 ? c : 1);
    int s = c;
    #pragma unroll
    for (int off = 32; off > 0; off >>= 1) s += __shfl_down(s, off);
    __shared__ int wsum[4];
    int wave = threadIdx.x >> 6, lane = threadIdx.x & 63;
    if (lane == 0) wsum[wave] = s;
    __syncthreads();
    if (threadIdx.x == 0) bsum[blockIdx.x] = wsum[0] + wsum[1] + wsum[2] + wsum[3];
}

// scan phase B: single small block scans 391 block sums -> block offsets + total
__global__ __launch_bounds__(512) void k_scan_top(const int* __restrict__ bsum,
                                                  int* __restrict__ boff,
                                                  int* __restrict__ rowptr) {
    __shared__ int sm[512];
    int t = threadIdx.x;
    int v = (t < NODE_BLOCKS) ? bsum[t] : 0;
    sm[t] = v;
    __syncthreads();
    for (int off = 1; off < 512; off <<= 1) {
        int u = (t >= off) ? sm[t - off] : 0;
        __syncthreads();
        sm[t] += u;
        __syncthreads();
    }
    if (t < NODE_BLOCKS) boff[t] = (t == 0) ? 0 : sm[t - 1];
    if (t == 511) rowptr[N_NODES] = sm[511];
}

// scan phase C: in-block exclusive scan + block offset -> rowptr
__global__ __launch_bounds__(256) void k_scan_local(const int* __restrict__ cnt,
                                                    const int* __restrict__ boff,
                                                    int* __restrict__ rowptr) {
    int i = blockIdx.x * 256 + threadIdx.x;
    int c = (i < N_NODES) ? cnt[i] : 0;
    int lane = threadIdx.x & 63;
    int wave = threadIdx.x >> 6;
    int x = c;
    #pragma unroll
    for (int off = 1; off < 64; off <<= 1) {
        int u = __shfl_up(x, off);
        if (lane >= off) x += u;
    }
    __shared__ int wsum[4];
    if (lane == 63) wsum[wave] = x;
    __syncthreads();
    int wo = 0;
    #pragma unroll
    for (int w = 0; w < 4; w++) if (w < wave) wo += wsum[w];
    if (i < N_NODES) rowptr[i] = boff[blockIdx.x] + wo + (x - c);
}

// Encoder EdgeConv per-edge MLP: 8 -> 32 -> 32 -> 2, relu x3.
// Writes result directly at CSR slot rowptr[dst]+rank[e].
__global__ __launch_bounds__(256) void k_enc_edge(const float* __restrict__ xn,
                                                  const int* __restrict__ ei,
                                                  const int* __restrict__ rowptr,
                                                  const int* __restrict__ rank,
                                                  float2* __restrict__ he,
                                                  const float* __restrict__ w1,
                                                  const float* __restrict__ b1,
                                                  const float* __restrict__ w2,
                                                  const float* __restrict__ b2,
                                                  const float* __restrict__ w3,
                                                  const float* __restrict__ b3) {
    int e = blockIdx.x * 256 + threadIdx.x;
    if (e >= N_EDGES) return;
    int s = ei[e];
    int d = ei[N_EDGES + e];
    float4 xi = ((const float4*)xn)[d];
    float4 xj = ((const float4*)xn)[s];
    float in[8];
    in[0] = xi.x; in[1] = xi.y; in[2] = xi.z; in[3] = xi.w;
    in[4] = xj.x - xi.x; in[5] = xj.y - xi.y; in[6] = xj.z - xi.z; in[7] = xj.w - xi.w;

    float h1[32];
    #pragma unroll
    for (int j = 0; j < 32; j++) h1[j] = b1[j];
    #pragma unroll
    for (int k = 0; k < 8; k++) {
        float v = in[k];
        #pragma unroll
        for (int j = 0; j < 32; j++) h1[j] = fmaf(v, w1[k * 32 + j], h1[j]);
    }
    #pragma unroll
    for (int j = 0; j < 32; j++) h1[j] = fmaxf(h1[j], 0.f);

    float h2[32];
    #pragma unroll
    for (int j = 0; j < 32; j++) h2[j] = b2[j];
    #pragma unroll
    for (int k = 0; k < 32; k++) {
        float v = h1[k];
        #pragma unroll
        for (int j = 0; j < 32; j++) h2[j] = fmaf(v, w2[k * 32 + j], h2[j]);
    }
    #pragma unroll
    for (int j = 0; j < 32; j++) h2[j] = fmaxf(h2[j], 0.f);

    float o0 = b3[0], o1 = b3[1];
    #pragma unroll
    for (int k = 0; k < 32; k++) {
        o0 = fmaf(h2[k], w3[2 * k + 0], o0);
        o1 = fmaf(h2[k], w3[2 * k + 1], o1);
    }
    int pos = rowptr[d] + rank[e];
    he[pos] = make_float2(fmaxf(o0, 0.f), fmaxf(o1, 0.f));
}

// mean-aggregate encoder outputs per node (contiguous CSR segment)
__global__ __launch_bounds__(256) void k_reduce_enc(const float2* __restrict__ he,
                                                    const int* __restrict__ rowptr,
                                                    const float* __restrict__ invcnt,
                                                    float2* __restrict__ agg1) {
    int i = blockIdx.x * 256 + threadIdx.x;
    if (i >= N_NODES) return;
    int p0 = rowptr[i], p1 = rowptr[i + 1];
    float a0 = 0.f, a1 = 0.f;
    for (int p = p0; p < p1; p++) {
        float2 h = he[p];
        a0 += h.x; a1 += h.y;
    }
    float ic = invcnt[i];
    agg1[i] = make_float2(a0 * ic, a1 * ic);
}

// Decoder EdgeConv per-edge MLP: 4 -> 32 -> 32 -> 4, relu on first two.
__global__ __launch_bounds__(256) void k_dec_edge(const float2* __restrict__ henc,
                                                  const int* __restrict__ ei,
                                                  const int* __restrict__ rowptr,
                                                  const int* __restrict__ rank,
                                                  float4* __restrict__ hd,
                                                  const float* __restrict__ w1,
                                                  const float* __restrict__ b1,
                                                  const float* __restrict__ w2,
                                                  const float* __restrict__ b2,
                                                  const float* __restrict__ w3,
                                                  const float* __restrict__ b3) {
    int e = blockIdx.x * 256 + threadIdx.x;
    if (e >= N_EDGES) return;
    int s = ei[e];
    int d = ei[N_EDGES + e];
    float2 hi = henc[d];
    float2 hj = henc[s];
    float in[4];
    in[0] = hi.x; in[1] = hi.y;
    in[2] = hj.x - hi.x; in[3] = hj.y - hi.y;

    float h1[32];
    #pragma unroll
    for (int j = 0; j < 32; j++) h1[j] = b1[j];
    #pragma unroll
    for (int k = 0; k < 4; k++) {
        float v = in[k];
        #pragma unroll
        for (int j = 0; j < 32; j++) h1[j] = fmaf(v, w1[k * 32 + j], h1[j]);
    }
    #pragma unroll
    for (int j = 0; j < 32; j++) h1[j] = fmaxf(h1[j], 0.f);

    float h2[32];
    #pragma unroll
    for (int j = 0; j < 32; j++) h2[j] = b2[j];
    #pragma unroll
    for (int k = 0; k < 32; k++) {
        float v = h1[k];
        #pragma unroll
        for (int j = 0; j < 32; j++) h2[j] = fmaf(v, w2[k * 32 + j], h2[j]);
    }
    #pragma unroll
    for (int j = 0; j < 32; j++) h2[j] = fmaxf(h2[j], 0.f);

    float o[4];
    #pragma unroll
    for (int j = 0; j < 4; j++) o[j] = b3[j];
    #pragma unroll
    for (int k = 0; k < 32; k++) {
        float v = h2[k];
        #pragma unroll
        for (int j = 0; j < 4; j++) o[j] = fmaf(v, w3[4 * k + j], o[j]);
    }
    int pos = rowptr[d] + rank[e];
    hd[pos] = make_float4(o[0], o[1], o[2], o[3]);  // no final relu
}

// mean-aggregate decoder outputs per node -> final output
__global__ __launch_bounds__(256) void k_reduce_dec(const float4* __restrict__ hd,
                                                    const int* __restrict__ rowptr,
                                                    const float* __restrict__ invcnt,
                                                    float4* __restrict__ out) {
    int i = blockIdx.x * 256 + threadIdx.x;
    if (i >= N_NODES) return;
    int p0 = rowptr[i], p1 = rowptr[i + 1];
    float a0 = 0.f, a1 = 0.f, a2 = 0.f, a3 = 0.f;
    for (int p = p0; p < p1; p++) {
        float4 h = hd[p];
        a0 += h.x; a1 += h.y; a2 += h.z; a3 += h.w;
    }
    float ic = invcnt[i];
    out[i] = make_float4(a0 * ic, a1 * ic, a2 * ic, a3 * ic);
}

extern "C" void kernel_launch(void* const* d_in, const int* in_sizes, int n_in,
                              void* d_out, int out_size, void* d_ws, size_t ws_size,
                              hipStream_t stream) {
    const float* x    = (const float*)d_in[0];
    const int*   ei   = (const int*)d_in[1];
    const float* bn_w = (const float*)d_in[2];
    const float* bn_b = (const float*)d_in[3];
    const float* ew1  = (const float*)d_in[4];
    const float* eb1  = (const float*)d_in[5];
    const float* ew2  = (const float*)d_in[6];
    const float* eb2  = (const float*)d_in[7];
    const float* ew3  = (const float*)d_in[8];
    const float* eb3  = (const float*)d_in[9];
    const float* dw1  = (const float*)d_in[10];
    const float* db1  = (const float*)d_in[11];
    const float* dw2  = (const float*)d_in[12];
    const float* db2  = (const float*)d_in[13];
    const float* dw3  = (const float*)d_in[14];
    const float* db3  = (const float*)d_in[15];

    char* ws = (char*)d_ws;
    double* stats  = (double*)(ws + OFF_STATS);
    int*    cnt    = (int*)(ws + OFF_CNT);
    int*    rowptr = (int*)(ws + OFF_ROWPTR);
    float*  invcnt = (float*)(ws + OFF_INVCNT);
    float2* agg1   = (float2*)(ws + OFF_AGG1);
    float*  xn     = (float*)(ws + OFF_XN);
    int*    rank   = (int*)(ws + OFF_RANK);
    int*    bsum   = (int*)(ws + OFF_BSUM);
    int*    boff   = (int*)(ws + OFF_BOFF);
    float2* he     = (float2*)(ws + OFF_H);
    float4* hd     = (float4*)(ws + OFF_H);   // aliased: enc reduce done before dec writes
    float4* out    = (float4*)d_out;

    // zero: stats (1 KB) + cnt (400 KB), contiguous
    hipMemsetAsync(ws, 0, OFF_CNT + N_NODES * sizeof(int), stream);

    const int edgeBlocks = (N_EDGES + 255) / 256;   // 12500

    k_rank<<<edgeBlocks, 256, 0, stream>>>(ei, cnt, rank);
    k_bn_stats<<<NODE_BLOCKS, 256, 0, stream>>>(x, stats);
    k_normalize<<<NODE_BLOCKS, 256, 0, stream>>>(x, stats, bn_w, bn_b, xn);
    k_scan_part<<<NODE_BLOCKS, 256, 0, stream>>>(cnt, bsum, invcnt);
    k_scan_top<<<1, 512, 0, stream>>>(bsum, boff, rowptr);
    k_scan_local<<<NODE_BLOCKS, 256, 0, stream>>>(cnt, boff, rowptr);
    k_enc_edge<<<edgeBlocks, 256, 0, stream>>>(xn, ei, rowptr, rank, he, ew1, eb1, ew2, eb2, ew3, eb3);
    k_reduce_enc<<<NODE_BLOCKS, 256, 0, stream>>>(he, rowptr, invcnt, agg1);
    k_dec_edge<<<edgeBlocks, 256, 0, stream>>>(agg1, ei, rowptr, rank, hd, dw1, db1, dw2, db2, dw3, db3);
    k_reduce_dec<<<NODE_BLOCKS, 256, 0, stream>>>(hd, rowptr, invcnt, out);
}